// Round 10
// baseline (113.654 us; speedup 1.0000x reference)
//
#include <hip/hip_runtime.h>

// Problem constants (from reference)
#define S0d   256
#define S1d   256
#define BONDd 32
#define BATCHd 2048
#define UNITSd 65536        // S0 * S1
#define NQ    16384         // UNITSd / 4 (vec4 granularity)

typedef float f32x4 __attribute__((ext_vector_type(4)));
typedef float f32x2 __attribute__((ext_vector_type(2)));
typedef unsigned int u32;
typedef u32 u32x4 __attribute__((ext_vector_type(4)));
typedef u32 u32x2 __attribute__((ext_vector_type(2)));

__device__ __forceinline__ u32 f2bf(float f) {   // RNE f32 -> bf16 bits
  u32 u = __float_as_uint(f);
  return (u + 0x7fffu + ((u >> 16) & 1u)) >> 16;
}
__device__ __forceinline__ float bf_lo(u32 w) { return __uint_as_float(w << 16); }
__device__ __forceinline__ float bf_hi(u32 w) { return __uint_as_float(w & 0xffff0000u); }

// ---------------------------------------------------------------------------
// Kernel A: compute G0,G1 (bf16-packed) + bias (bf16) into d_ws.
// Layout: GB[NQ] of u32x4  (g0[e0..3], g1[e0..3] for vec4 q)   = 256 KiB
//         Bb[NQ] of u32x2  (bias[e0..3])                        = 128 KiB
// ---------------------------------------------------------------------------
__global__ __launch_bounds__(256) void precompute_GB(
    const float* __restrict__ core1, const float* __restrict__ core2,
    const float* __restrict__ bias, u32x4* __restrict__ GB, u32x2* __restrict__ Bb) {
  const int q = blockIdx.x * 256 + threadIdx.x;   // 0..NQ-1
  const int a = q >> 6;                           // row in S0
  const int c0 = (q & 63) * 4;                    // first col of vec4
  // s[p] = core1[0,a,p] + core1[1,a,p]
  f32x4 sv[BONDd / 4];
  const f32x4* c10 = (const f32x4*)(core1 + a * BONDd);
  const f32x4* c11 = (const f32x4*)(core1 + S0d * BONDd + a * BONDd);
#pragma unroll
  for (int qq = 0; qq < BONDd / 4; ++qq) sv[qq] = c10[qq] + c11[qq];
  float g0[4], g1[4];
#pragma unroll
  for (int e = 0; e < 4; ++e) {
    const f32x4* r0 = (const f32x4*)(core2 + (c0 + e) * BONDd);
    const f32x4* r1 = (const f32x4*)(core2 + S1d * BONDd + (c0 + e) * BONDd);
    float a0 = 0.f, a1 = 0.f;
#pragma unroll
    for (int qq = 0; qq < BONDd / 4; ++qq) {
      f32x4 s = sv[qq], v0 = r0[qq], v1 = r1[qq];
      a0 = fmaf(s.x, v0.x, fmaf(s.y, v0.y, fmaf(s.z, v0.z, fmaf(s.w, v0.w, a0))));
      a1 = fmaf(s.x, v1.x, fmaf(s.y, v1.y, fmaf(s.z, v1.z, fmaf(s.w, v1.w, a1))));
    }
    g0[e] = a0; g1[e] = a1;
  }
  u32x4 gb;
  gb.x = f2bf(g0[0]) | (f2bf(g0[1]) << 16);
  gb.y = f2bf(g0[2]) | (f2bf(g0[3]) << 16);
  gb.z = f2bf(g1[0]) | (f2bf(g1[1]) << 16);
  gb.w = f2bf(g1[2]) | (f2bf(g1[3]) << 16);
  GB[q] = gb;
  const f32x4 bs = *(const f32x4*)(bias + q * 4);
  u32x2 bb;
  bb.x = f2bf(bs.x) | (f2bf(bs.y) << 16);
  bb.y = f2bf(bs.z) | (f2bf(bs.w) << 16);
  Bb[q] = bb;
}

// ---------------------------------------------------------------------------
// Kernel B: td_wave structure (R6 winner) with bf16-packed G/bias reads.
// Per store: 24 B of reads (was 48 B), 2 loads (was 3). Store pattern,
// pipelining, NT stores, grid — all identical to td_wave.
// Wave segment = 4096 vec4s; each iteration covers 64 vec4s (lane-contig
// 1 KiB burst), 64 iterations total.
// ---------------------------------------------------------------------------
__global__ __launch_bounds__(256) void td_wave_bf(
    const float* __restrict__ inputs, const u32x4* __restrict__ GB,
    const u32x2* __restrict__ Bb, float* __restrict__ out) {
  const int b = blockIdx.x;
  const f32x2 x = *(const f32x2*)(inputs + b * 2);   // uniform per block
  const int wave = threadIdx.x >> 6;
  const int lane = threadIdx.x & 63;
  const int q0 = wave * (NQ / 4) + lane;             // vec4 index, +64/iter
  f32x4* outv = (f32x4*)(out + (size_t)b * UNITSd) + q0;

  u32x4 gbn = GB[q0];
  u32x2 bbn = Bb[q0];
#pragma unroll 4
  for (int it = 0; it < 63; ++it) {
    const u32x4 gb = gbn; const u32x2 bb = bbn;
    gbn = GB[q0 + (it + 1) * 64];
    bbn = Bb[q0 + (it + 1) * 64];
    f32x4 r;
    r.x = fmaxf(fmaf(x.y, bf_lo(gb.z), fmaf(x.x, bf_lo(gb.x), bf_lo(bb.x))), 0.f);
    r.y = fmaxf(fmaf(x.y, bf_hi(gb.z), fmaf(x.x, bf_hi(gb.x), bf_hi(bb.x))), 0.f);
    r.z = fmaxf(fmaf(x.y, bf_lo(gb.w), fmaf(x.x, bf_lo(gb.y), bf_lo(bb.y))), 0.f);
    r.w = fmaxf(fmaf(x.y, bf_hi(gb.w), fmaf(x.x, bf_hi(gb.y), bf_hi(bb.y))), 0.f);
    __builtin_nontemporal_store(r, outv + it * 64);
  }
  {  // epilogue it = 63
    f32x4 r;
    r.x = fmaxf(fmaf(x.y, bf_lo(gbn.z), fmaf(x.x, bf_lo(gbn.x), bf_lo(bbn.x))), 0.f);
    r.y = fmaxf(fmaf(x.y, bf_hi(gbn.z), fmaf(x.x, bf_hi(gbn.x), bf_hi(bbn.x))), 0.f);
    r.z = fmaxf(fmaf(x.y, bf_lo(gbn.w), fmaf(x.x, bf_lo(gbn.y), bf_lo(bbn.y))), 0.f);
    r.w = fmaxf(fmaf(x.y, bf_hi(gbn.w), fmaf(x.x, bf_hi(gbn.y), bf_hi(bbn.y))), 0.f);
    __builtin_nontemporal_store(r, outv + 63 * 64);
  }
}

// ---------------------------------------------------------------------------
// Fallback (only if ws_size < 384 KiB): recompute this thread's G in prologue
// ---------------------------------------------------------------------------
__global__ __launch_bounds__(256) void td_fused(
    const float* __restrict__ inputs, const float* __restrict__ core1,
    const float* __restrict__ core2, const float* __restrict__ bias,
    float* __restrict__ out) {
  const int u = blockIdx.x * 1024 + threadIdx.x * 4;
  const int a = u >> 8;
  const int c = u & 255;
  float s[BONDd];
#pragma unroll
  for (int p = 0; p < BONDd; ++p)
    s[p] = core1[a * BONDd + p] + core1[S0d * BONDd + a * BONDd + p];
  float g0[4], g1[4];
#pragma unroll
  for (int cc = 0; cc < 4; ++cc) {
    float a0 = 0.f, a1 = 0.f;
#pragma unroll
    for (int p = 0; p < BONDd; ++p) {
      a0 = fmaf(s[p], core2[(c + cc) * BONDd + p], a0);
      a1 = fmaf(s[p], core2[S1d * BONDd + (c + cc) * BONDd + p], a1);
    }
    g0[cc] = a0; g1[cc] = a1;
  }
  const f32x4 bs = *(const f32x4*)(bias + u);
  const int b0 = blockIdx.y * 64;
  float* outp = out + (size_t)b0 * UNITSd + u;
#pragma unroll 4
  for (int k = 0; k < 64; ++k) {
    const f32x2 x = *(const f32x2*)(inputs + (b0 + k) * 2);
    f32x4 r;
    r.x = fmaxf(fmaf(x.y, g1[0], fmaf(x.x, g0[0], bs.x)), 0.f);
    r.y = fmaxf(fmaf(x.y, g1[1], fmaf(x.x, g0[1], bs.y)), 0.f);
    r.z = fmaxf(fmaf(x.y, g1[2], fmaf(x.x, g0[2], bs.z)), 0.f);
    r.w = fmaxf(fmaf(x.y, g1[3], fmaf(x.x, g0[3], bs.w)), 0.f);
    *(f32x4*)outp = r;
    outp += UNITSd;
  }
}

extern "C" void kernel_launch(void* const* d_in, const int* in_sizes, int n_in,
                              void* d_out, int out_size, void* d_ws, size_t ws_size,
                              hipStream_t stream) {
  const float* inputs = (const float*)d_in[0];  // (2048, 2)
  const float* core1  = (const float*)d_in[1];  // (2, 256, 32)
  const float* core2  = (const float*)d_in[2];  // (2, 256, 32)
  const float* bias   = (const float*)d_in[3];  // (256, 256)
  float* out = (float*)d_out;                   // (2048, 65536)

  const size_t need = (size_t)NQ * 16 + (size_t)NQ * 8;   // 384 KiB
  if (ws_size >= need) {
    u32x4* GB = (u32x4*)d_ws;
    u32x2* Bb = (u32x2*)((char*)d_ws + (size_t)NQ * 16);
    precompute_GB<<<NQ / 256, 256, 0, stream>>>(core1, core2, bias, GB, Bb);
    td_wave_bf<<<BATCHd, 256, 0, stream>>>(inputs, GB, Bb, out);
  } else {
    td_fused<<<dim3(UNITSd / 1024, BATCHd / 64), 256, 0, stream>>>(
        inputs, core1, core2, bias, out);
  }
}